// Round 1
// baseline (53.209 us; speedup 1.0000x reference)
//
#include <hip/hip_runtime.h>
#include <hip/hip_bf16.h>

// Binary-quantization entropy per row.
// values: [B=256, N=262144] fp32. Per row: c1 = #positives, c0 = N - c1,
// p = c / (N + 1e-8), H = -sum(p * log2(p + 1e-10)) over bins with p > 0.
// Memory-bound streaming count; one block per row.

#define B_ROWS 256
#define N_PER_ROW 262144
#define BLOCK_THREADS 1024
#define WAVES_PER_BLOCK (BLOCK_THREADS / 64)

__global__ __launch_bounds__(BLOCK_THREADS) void entropy_rows_kernel(
    const float* __restrict__ values, float* __restrict__ out) {
  const int row = blockIdx.x;
  const int tid = threadIdx.x;

  const float4* rowp =
      reinterpret_cast<const float4*>(values + (size_t)row * N_PER_ROW);
  const int n_vec4 = N_PER_ROW / 4;               // 65536 float4 per row
  const int iters = n_vec4 / BLOCK_THREADS;       // 64 iterations per thread

  int c = 0;
#pragma unroll 4
  for (int i = 0; i < iters; ++i) {
    float4 v = rowp[(size_t)i * BLOCK_THREADS + tid];
    c += (v.x > 0.0f) + (v.y > 0.0f) + (v.z > 0.0f) + (v.w > 0.0f);
  }

  // wave (64-lane) reduction
#pragma unroll
  for (int off = 32; off > 0; off >>= 1) c += __shfl_down(c, off, 64);

  // cross-wave reduction via LDS
  __shared__ int wsum[WAVES_PER_BLOCK];
  const int lane = tid & 63;
  const int wave = tid >> 6;
  if (lane == 0) wsum[wave] = c;
  __syncthreads();

  if (tid == 0) {
    int c1 = 0;
#pragma unroll
    for (int w = 0; w < WAVES_PER_BLOCK; ++w) c1 += wsum[w];
    int c0 = N_PER_ROW - c1;
    // n + 1e-8 rounds to n in fp32, matching the jnp fp32 math.
    const float inv_n = 1.0f / (float)N_PER_ROW;
    float p0 = (float)c0 * inv_n;
    float p1 = (float)c1 * inv_n;
    float t0 = (p0 > 0.0f) ? p0 * log2f(p0 + 1e-10f) : 0.0f;
    float t1 = (p1 > 0.0f) ? p1 * log2f(p1 + 1e-10f) : 0.0f;
    out[row] = -(t0 + t1);
  }
}

extern "C" void kernel_launch(void* const* d_in, const int* in_sizes, int n_in,
                              void* d_out, int out_size, void* d_ws, size_t ws_size,
                              hipStream_t stream) {
  const float* values = (const float*)d_in[0];
  float* out = (float*)d_out;
  entropy_rows_kernel<<<B_ROWS, BLOCK_THREADS, 0, stream>>>(values, out);
}

// Round 2
// 44.843 us; speedup vs baseline: 1.1866x; 1.1866x over previous
//
#include <hip/hip_runtime.h>
#include <hip/hip_bf16.h>

// Binary-quantization entropy per row, two-stage.
// values: [B=256, N=262144] fp32. c1 = #positives per row, c0 = N - c1,
// p = c / (N + 1e-8), H = -sum(p * log2(p + 1e-10)) over bins with p > 0.
//
// Stage 1: 2048 blocks x 256 threads (8 blocks/CU -> 32 waves/CU resident),
//          each block counts positives in one contiguous 1/8-row slice,
//          writes one int partial to d_ws. No atomics, fully deterministic.
// Stage 2: 1 block x 256 threads; thread r sums its row's 8 partials and
//          computes the 2-bin entropy.

#define B_ROWS 256
#define N_PER_ROW 262144
#define SLICES 8
#define SLICE_ELEMS (N_PER_ROW / SLICES)      // 32768 floats = 8192 float4
#define BLOCK_THREADS 256
#define WAVES_PER_BLOCK (BLOCK_THREADS / 64)  // 4
#define ITERS (SLICE_ELEMS / 4 / BLOCK_THREADS)  // 32 float4 per thread

__global__ __launch_bounds__(BLOCK_THREADS) void count_slices_kernel(
    const float* __restrict__ values, int* __restrict__ partial) {
  const int blk = blockIdx.x;          // 0..2047
  const int row = blk >> 3;
  const int slice = blk & (SLICES - 1);
  const int tid = threadIdx.x;

  const float4* p = reinterpret_cast<const float4*>(
      values + (size_t)row * N_PER_ROW + (size_t)slice * SLICE_ELEMS);

  int c = 0;
#pragma unroll 8
  for (int i = 0; i < ITERS; ++i) {
    float4 v = p[i * BLOCK_THREADS + tid];
    c += (v.x > 0.0f) + (v.y > 0.0f) + (v.z > 0.0f) + (v.w > 0.0f);
  }

  // 64-lane wave reduction
#pragma unroll
  for (int off = 32; off > 0; off >>= 1) c += __shfl_down(c, off, 64);

  __shared__ int wsum[WAVES_PER_BLOCK];
  const int lane = tid & 63;
  const int wave = tid >> 6;
  if (lane == 0) wsum[wave] = c;
  __syncthreads();

  if (tid == 0) {
    int s = wsum[0];
#pragma unroll
    for (int w = 1; w < WAVES_PER_BLOCK; ++w) s += wsum[w];
    partial[blk] = s;
  }
}

__global__ __launch_bounds__(B_ROWS) void entropy_finalize_kernel(
    const int* __restrict__ partial, float* __restrict__ out) {
  const int row = threadIdx.x;  // 0..255
  int c1 = 0;
#pragma unroll
  for (int s = 0; s < SLICES; ++s) c1 += partial[row * SLICES + s];
  const int c0 = N_PER_ROW - c1;
  // n + 1e-8 rounds to n in fp32, matching jnp's fp32 math.
  const float inv_n = 1.0f / (float)N_PER_ROW;
  const float p0 = (float)c0 * inv_n;
  const float p1 = (float)c1 * inv_n;
  const float t0 = (p0 > 0.0f) ? p0 * log2f(p0 + 1e-10f) : 0.0f;
  const float t1 = (p1 > 0.0f) ? p1 * log2f(p1 + 1e-10f) : 0.0f;
  out[row] = -(t0 + t1);
}

extern "C" void kernel_launch(void* const* d_in, const int* in_sizes, int n_in,
                              void* d_out, int out_size, void* d_ws, size_t ws_size,
                              hipStream_t stream) {
  const float* values = (const float*)d_in[0];
  float* out = (float*)d_out;
  int* partial = (int*)d_ws;  // 2048 ints = 8 KB, all slots written by stage 1

  count_slices_kernel<<<B_ROWS * SLICES, BLOCK_THREADS, 0, stream>>>(values, partial);
  entropy_finalize_kernel<<<1, B_ROWS, 0, stream>>>(partial, out);
}